// Round 9
// baseline (205.681 us; speedup 1.0000x reference)
//
#include <hip/hip_runtime.h>
#include <cstddef>
#include <cstdint>

using half4v   = __attribute__((ext_vector_type(4))) _Float16;
using half8    = __attribute__((ext_vector_type(8))) _Float16;
using floatx4  = __attribute__((ext_vector_type(4))) float;
using floatx16 = __attribute__((ext_vector_type(16))) float;

#define B_   2
#define NQ_  2048
#define DM   1024
#define NH_  16
#define DH_  64
#define NTILES 32   // NKV / 64

// async global->LDS, 16B per lane. LDS dest = wave-uniform base + lane*16.
__device__ __forceinline__ void async16(const _Float16* g, _Float16* l) {
    __builtin_amdgcn_global_load_lds(
        (const __attribute__((address_space(1))) unsigned int*)g,
        (__attribute__((address_space(3))) unsigned int*)l, 16, 0, 0);
}

// RNE pack 2 f32 -> u32 of 2 f16 (matches baseline numerics).
__device__ __forceinline__ unsigned pkh(float a, float b) {
    union { _Float16 h[2]; unsigned u; } x;
    x.h[0] = (_Float16)a; x.h[1] = (_Float16)b;
    return x.u;
}

// ---------------------------------------------------------------------------
// Fused fp32 -> fp16 convert for all 6 tensors (1 launch).
// ---------------------------------------------------------------------------
__global__ __launch_bounds__(256) void cvt_all(
        const float* __restrict__ q,  const float* __restrict__ kv,
        const float* __restrict__ wq, const float* __restrict__ wk,
        const float* __restrict__ wv, const float* __restrict__ wo,
        _Float16* __restrict__ dq,  _Float16* __restrict__ dkv,
        _Float16* __restrict__ dwq, _Float16* __restrict__ dwk,
        _Float16* __restrict__ dwv, _Float16* __restrict__ dwo) {
    int blk = blockIdx.x;
    const float* s;
    _Float16* d;
    int base;
    if (blk < 2048)      { s = q;  d = dq;  base = blk; }
    else if (blk < 4096) { s = kv; d = dkv; base = blk - 2048; }
    else if (blk < 4608) { s = wq; d = dwq; base = blk - 4096; }
    else if (blk < 5120) { s = wk; d = dwk; base = blk - 4608; }
    else if (blk < 5632) { s = wv; d = dwv; base = blk - 5120; }
    else                 { s = wo; d = dwo; base = blk - 5632; }
    int i = base * 256 + threadIdx.x;
    const float4* s4 = (const float4*)s;
    float4 a = s4[2 * i], b = s4[2 * i + 1];
    half8 h;
    h[0] = (_Float16)a.x; h[1] = (_Float16)a.y; h[2] = (_Float16)a.z; h[3] = (_Float16)a.w;
    h[4] = (_Float16)b.x; h[5] = (_Float16)b.y; h[6] = (_Float16)b.z; h[7] = (_Float16)b.w;
    ((half8*)d)[i] = h;
}

// ---------------------------------------------------------------------------
// Fused QKV projection GEMM, 768 blocks (3/CU resident).
// Q scale = 0.125*log2(e) so attn softmax uses bare exp2.
// ---------------------------------------------------------------------------
__global__ __launch_bounds__(256, 3) void proj_qkv(
        const _Float16* __restrict__ q16, const _Float16* __restrict__ kv16,
        const _Float16* __restrict__ wqp, const _Float16* __restrict__ wkp,
        const _Float16* __restrict__ wvp,
        const float* __restrict__ bqp, const float* __restrict__ bkp,
        const float* __restrict__ bvp,
        _Float16* __restrict__ qh, _Float16* __restrict__ kh,
        _Float16* __restrict__ vt) {
    __shared__ _Float16 As[128 * 64];   // 16 KB
    __shared__ _Float16 Bs[128 * 64];   // 16 KB

    const int which = blockIdx.x >> 8;
    const int sub = blockIdx.x & 255;
    const _Float16* A = (which == 0) ? q16 : kv16;
    const _Float16* W = (which == 0) ? wqp : (which == 1) ? wkp : wvp;
    const float* bias = (which == 0) ? bqp : (which == 1) ? bkp : bvp;

    const int t = threadIdx.x;
    const int w = t >> 6, lane = t & 63;
    const int r16 = lane & 15, quad = lane >> 4;
    const int bm = (sub & 7) * 4 + ((sub >> 3) & 3);
    const int bn = sub >> 5;
    const int m0 = bm * 128, n0 = bn * 128;
    const int wm = w >> 1, wn = w & 1;

    floatx4 acc[4][4];
#pragma unroll
    for (int i = 0; i < 4; i++)
#pragma unroll
        for (int j = 0; j < 4; j++)
#pragma unroll
            for (int r = 0; r < 4; r++) acc[i][j][r] = 0.f;

    const int ph0 = quad ^ (r16 & 7), ph1 = ph0 ^ 4;

    for (int k0 = 0; k0 < DM; k0 += 64) {
        __syncthreads();
#pragma unroll
        for (int i = 0; i < 4; i++) {
            int P = i * 256 + t;
            int m = P >> 3, c = (P & 7) ^ (m & 7);
            async16(A + (size_t)(m0 + m) * DM + k0 + c * 8, &As[P * 8]);
            async16(W + (size_t)(n0 + m) * DM + k0 + c * 8, &Bs[P * 8]);
        }
        asm volatile("s_waitcnt vmcnt(0)" ::: "memory");
        __syncthreads();

        half8 af[4][2], bf[4][2];
#pragma unroll
        for (int mi = 0; mi < 4; mi++) {
            int m = wm * 64 + mi * 16 + r16;
            af[mi][0] = ((const half8*)As)[m * 8 + ph0];
            af[mi][1] = ((const half8*)As)[m * 8 + ph1];
        }
#pragma unroll
        for (int ni = 0; ni < 4; ni++) {
            int n = wn * 64 + ni * 16 + r16;
            bf[ni][0] = ((const half8*)Bs)[n * 8 + ph0];
            bf[ni][1] = ((const half8*)Bs)[n * 8 + ph1];
        }
#pragma unroll
        for (int kd = 0; kd < 2; kd++)
#pragma unroll
            for (int mi = 0; mi < 4; mi++)
#pragma unroll
                for (int ni = 0; ni < 4; ni++)
                    acc[mi][ni] = __builtin_amdgcn_mfma_f32_16x16x32_f16(
                        af[mi][kd], bf[ni][kd], acc[mi][ni], 0, 0, 0);
    }

    if (which < 2) {
        _Float16* C = (which == 0) ? qh : kh;
        // 0.125 * log2(e): softmax downstream uses exp2 directly.
        const float esc = (which == 0) ? 0.18033688011112042f : 1.0f;
#pragma unroll
        for (int mi = 0; mi < 4; mi++)
#pragma unroll
            for (int r = 0; r < 4; r++) {
                int row = m0 + wm * 64 + mi * 16 + quad * 4 + r;
#pragma unroll
                for (int ni = 0; ni < 4; ni++) {
                    int col = n0 + wn * 64 + ni * 16 + r16;
                    C[(size_t)row * DM + col] = (_Float16)((acc[mi][ni][r] + bias[col]) * esc);
                }
            }
    } else {
#pragma unroll
        for (int mi = 0; mi < 4; mi++) {
            int krow = m0 + wm * 64 + mi * 16 + quad * 4;
            int bb = krow >> 11, kk = krow & 2047;
#pragma unroll
            for (int ni = 0; ni < 4; ni++) {
                int col = n0 + wn * 64 + ni * 16 + r16;
                int hh = col >> 6, dd = col & 63;
                float bv = bias[col];
                half4v pk;
#pragma unroll
                for (int r = 0; r < 4; r++) pk[r] = (_Float16)(acc[mi][ni][r] + bv);
                *(half4v*)&vt[((size_t)((bb * NH_ + hh) * DH_ + dd)) * NQ_ + kk] = pk;
            }
        }
    }
}

// ---------------------------------------------------------------------------
// Flash attention, fixed-max softmax. R9 = R8 resubmitted unchanged (R8's
// bench died of infra, not the kernel). R5-verified dataflow; one contained
// re-tile: block 256->128 thr (2 waves), qtile 128->64, grid 512->1024.
// Per-wave compute byte-identical to R5 (32q x 64k, same swizzles); sync
// topology halves (2-wave barriers) and 4 independent block pipelines/CU
// (40KB LDS each) overlap each other's staging drains.
// ---------------------------------------------------------------------------
__global__ __launch_bounds__(128, 2) void attn_mfma(const _Float16* __restrict__ Qg,
                                                    const _Float16* __restrict__ Kg,
                                                    const _Float16* __restrict__ Vt,
                                                    _Float16* __restrict__ Og) {
    __shared__ _Float16 Qs[64 * 64];     //  8 KB: [64 q][64 d], chunk^(q&7)
    __shared__ _Float16 Ks[2][64 * 64];  // 16 KB: [64 k][64 d], chunk^(k&7)
    __shared__ _Float16 Vs[2][64 * 64];  // 16 KB: [64 d][64 k], chunk^(d&7)

    const int t = threadIdx.x, w = t >> 6, lane = t & 63;
    const int l31 = lane & 31, hi = lane >> 5;
    const int blk = blockIdx.x;
    const int bh = (blk & 7) * 4 + ((blk >> 3) & 3);
    const int qt = blk >> 5;                      // 0..31 (64 q rows each)
    const int b = bh >> 4, h = bh & 15;

    const _Float16* qbase = Qg + (size_t)(b * NQ_ + qt * 64) * DM + h * DH_;
    const _Float16* kbase = Kg + (size_t)(b * NQ_) * DM + h * DH_;
    const _Float16* vbase = Vt + (size_t)bh * DH_ * NQ_;

    // prologue: stage Q (64x64) + K0/V0 (4 rounds each at 128 threads)
#pragma unroll
    for (int r = 0; r < 4; r++) {
        int P = r * 128 + t;
        int m = P >> 3, c = (P & 7) ^ (m & 7);
        async16(qbase + (size_t)m * DM + c * 8, &Qs[P * 8]);
        async16(kbase + (size_t)m * DM + c * 8, &Ks[0][P * 8]);
        async16(vbase + (size_t)m * NQ_ + c * 8, &Vs[0][P * 8]);
    }
    asm volatile("s_waitcnt vmcnt(0)" ::: "memory");
    __syncthreads();

    // hoist Q B-frags: col q = w*32 + l31, slice s covers d = s*16 + hi*8 + j
    half8 qf[4];
    {
        int qr = w * 32 + l31;
#pragma unroll
        for (int s = 0; s < 4; s++)
            qf[s] = ((const half8*)Qs)[qr * 8 + ((s * 2 + hi) ^ (qr & 7))];
    }

    floatx16 oacc0, oacc1;   // O^T [64 d][32 q]: d-blocks 0/1
#pragma unroll
    for (int r = 0; r < 16; r++) { oacc0[r] = 0.f; oacc1[r] = 0.f; }
    float lacc = 0.f;

    for (int kt = 0; kt < NTILES; kt++) {
        const int cur = kt & 1;
        asm volatile("s_waitcnt vmcnt(0)" ::: "memory");  // tile-kt loads landed
        __syncthreads();                                  // both waves' slices landed

        if (kt + 1 < NTILES) {   // prefetch tile kt+1 into other buffer
            const int nxt = cur ^ 1;
#pragma unroll
            for (int r = 0; r < 4; r++) {
                int P = r * 128 + t;
                int m = P >> 3, c = (P & 7) ^ (m & 7);
                async16(kbase + (size_t)((kt + 1) * 64 + m) * DM + c * 8, &Ks[nxt][P * 8]);
                async16(vbase + (size_t)m * NQ_ + (kt + 1) * 64 + c * 8, &Vs[nxt][P * 8]);
            }
        }

#pragma unroll
        for (int kh2 = 0; kh2 < 2; kh2++) {
            // S^T[32k x 32q] = K(half) . Q^T : A rows k = kh2*32+l31
            floatx16 sacc;
#pragma unroll
            for (int r = 0; r < 16; r++) sacc[r] = 0.f;
            __builtin_amdgcn_s_setprio(1);
#pragma unroll
            for (int s = 0; s < 4; s++) {
                half8 kf = ((const half8*)Ks[cur])[(kh2 * 32 + l31) * 8 + ((s * 2 + hi) ^ (l31 & 7))];
                sacc = __builtin_amdgcn_mfma_f32_32x32x16_f16(kf, qf[s], sacc, 0, 0, 0);
            }
            __builtin_amdgcn_s_setprio(0);

            // softmax (fixed max): p = exp2(s') (log2e pre-folded into Q)
#pragma unroll
            for (int r = 0; r < 16; r++) sacc[r] = __builtin_amdgcn_exp2f(sacc[r]);
#pragma unroll
            for (int r = 0; r < 16; r++) lacc += sacc[r];

            // P -> PV B-frags in registers via v_permlane32_swap_b32.
            half8 pf0, pf1;
            {
                unsigned a0 = pkh(sacc[0], sacc[1]),  a1 = pkh(sacc[2], sacc[3]);
                unsigned b0 = pkh(sacc[4], sacc[5]),  b1 = pkh(sacc[6], sacc[7]);
                asm("v_permlane32_swap_b32 %0, %1" : "+v"(a0), "+v"(b0));
                asm("v_permlane32_swap_b32 %0, %1" : "+v"(a1), "+v"(b1));
                union { unsigned u[4]; half8 hh; } pu;
                pu.u[0] = a0; pu.u[1] = a1; pu.u[2] = b0; pu.u[3] = b1;
                pf0 = pu.hh;
            }
            {
                unsigned a0 = pkh(sacc[8], sacc[9]),   a1 = pkh(sacc[10], sacc[11]);
                unsigned b0 = pkh(sacc[12], sacc[13]), b1 = pkh(sacc[14], sacc[15]);
                asm("v_permlane32_swap_b32 %0, %1" : "+v"(a0), "+v"(b0));
                asm("v_permlane32_swap_b32 %0, %1" : "+v"(a1), "+v"(b1));
                union { unsigned u[4]; half8 hh; } pu;
                pu.u[0] = a0; pu.u[1] = a1; pu.u[2] = b0; pu.u[3] = b1;
                pf1 = pu.hh;
            }

            // O^T += V^T[:, kh2-half] . P^T
            __builtin_amdgcn_s_setprio(1);
#pragma unroll
            for (int s2 = 0; s2 < 2; s2++) {
                half8 pfk = s2 ? pf1 : pf0;
                {
                    half8 vf = ((const half8*)Vs[cur])[(0 * 32 + l31) * 8 + ((kh2 * 4 + s2 * 2 + hi) ^ (l31 & 7))];
                    oacc0 = __builtin_amdgcn_mfma_f32_32x32x16_f16(vf, pfk, oacc0, 0, 0, 0);
                }
                {
                    half8 vf = ((const half8*)Vs[cur])[(1 * 32 + l31) * 8 + ((kh2 * 4 + s2 * 2 + hi) ^ (l31 & 7))];
                    oacc1 = __builtin_amdgcn_mfma_f32_32x32x16_f16(vf, pfk, oacc1, 0, 0, 0);
                }
            }
            __builtin_amdgcn_s_setprio(0);
        }
    }

    // epilogue: l = own 16 rows + partner's 16 (lane^32), normalize, store.
    {
        float lt = lacc + __shfl_xor(lacc, 32);
        float linv = 1.f / lt;
        int qrow = b * NQ_ + qt * 64 + w * 32 + l31;
#pragma unroll
        for (int g = 0; g < 4; g++) {
            half4v o0, o1;
#pragma unroll
            for (int j = 0; j < 4; j++) {
                o0[j] = (_Float16)(oacc0[g * 4 + j] * linv);
                o1[j] = (_Float16)(oacc1[g * 4 + j] * linv);
            }
            int d0 = g * 8 + 4 * hi;
            *(half4v*)&Og[(size_t)qrow * DM + h * DH_ + d0] = o0;
            *(half4v*)&Og[(size_t)qrow * DM + h * DH_ + 32 + d0] = o1;
        }
    }
}

// ---------------------------------------------------------------------------
// O projection: out[4096,1024] fp32 = ao @ Wo^T + bo. 128x64 tile, grid 512.
// ---------------------------------------------------------------------------
__global__ __launch_bounds__(256, 4) void gemm_o(const _Float16* __restrict__ A,
                                                 const _Float16* __restrict__ W,
                                                 const float* __restrict__ bias,
                                                 float* __restrict__ C) {
    __shared__ _Float16 As[128 * 64];   // 16 KB
    __shared__ _Float16 Bs[64 * 64];    //  8 KB

    const int t = threadIdx.x;
    const int w = t >> 6, lane = t & 63;
    const int r16 = lane & 15, quad = lane >> 4;
    const int blk = blockIdx.x;
    const int bm = (blk & 7) * 4 + ((blk >> 3) & 3);   // 0..31
    const int bn = blk >> 5;                            // 0..15
    const int m0 = bm * 128, n0 = bn * 64;
    const int wm = w >> 1, wn = w & 1;

    floatx4 acc[4][2];
#pragma unroll
    for (int i = 0; i < 4; i++)
#pragma unroll
        for (int j = 0; j < 2; j++)
#pragma unroll
            for (int r = 0; r < 4; r++) acc[i][j][r] = 0.f;

    const int ph0 = quad ^ (r16 & 7), ph1 = ph0 ^ 4;

    for (int k0 = 0; k0 < DM; k0 += 64) {
        __syncthreads();
#pragma unroll
        for (int i = 0; i < 4; i++) {
            int P = i * 256 + t;
            int m = P >> 3, c = (P & 7) ^ (m & 7);
            async16(A + (size_t)(m0 + m) * DM + k0 + c * 8, &As[P * 8]);
        }
#pragma unroll
        for (int i = 0; i < 2; i++) {
            int P = i * 256 + t;
            int m = P >> 3, c = (P & 7) ^ (m & 7);
            async16(W + (size_t)(n0 + m) * DM + k0 + c * 8, &Bs[P * 8]);
        }
        asm volatile("s_waitcnt vmcnt(0)" ::: "memory");
        __syncthreads();

        half8 af[4][2], bf[2][2];
#pragma unroll
        for (int mi = 0; mi < 4; mi++) {
            int m = wm * 64 + mi * 16 + r16;
            af[mi][0] = ((const half8*)As)[m * 8 + ph0];
            af[mi][1] = ((const half8*)As)[m * 8 + ph1];
        }
#pragma unroll
        for (int ni = 0; ni < 2; ni++) {
            int n = wn * 32 + ni * 16 + r16;
            bf[ni][0] = ((const half8*)Bs)[n * 8 + ph0];
            bf[ni][1] = ((const half8*)Bs)[n * 8 + ph1];
        }
#pragma unroll
        for (int kd = 0; kd < 2; kd++)
#pragma unroll
            for (int mi = 0; mi < 4; mi++)
#pragma unroll
                for (int ni = 0; ni < 2; ni++)
                    acc[mi][ni] = __builtin_amdgcn_mfma_f32_16x16x32_f16(
                        af[mi][kd], bf[ni][kd], acc[mi][ni], 0, 0, 0);
    }

#pragma unroll
    for (int mi = 0; mi < 4; mi++)
#pragma unroll
        for (int r = 0; r < 4; r++) {
            int row = m0 + wm * 64 + mi * 16 + quad * 4 + r;
#pragma unroll
            for (int ni = 0; ni < 2; ni++) {
                int col = n0 + wn * 32 + ni * 16 + r16;
                C[(size_t)row * DM + col] = acc[mi][ni][r] + bias[col];
            }
        }
}

// ---------------------------------------------------------------------------
extern "C" void kernel_launch(void* const* d_in, const int* in_sizes, int n_in,
                              void* d_out, int out_size, void* d_ws, size_t ws_size,
                              hipStream_t stream) {
    const float* q  = (const float*)d_in[0];
    const float* kv = (const float*)d_in[1];
    const float* Wq = (const float*)d_in[2];
    const float* bq = (const float*)d_in[3];
    const float* Wk = (const float*)d_in[4];
    const float* bk = (const float*)d_in[5];
    const float* Wv = (const float*)d_in[6];
    const float* bv = (const float*)d_in[7];
    const float* Wo = (const float*)d_in[8];
    const float* bo = (const float*)d_in[9];

    char* ws = (char*)d_ws;
    _Float16* q16  = (_Float16*)(ws);
    _Float16* kv16 = (_Float16*)(ws + (size_t)(8  << 20));
    _Float16* w16q = (_Float16*)(ws + (size_t)(16 << 20));
    _Float16* w16k = (_Float16*)(ws + (size_t)(18 << 20));
    _Float16* w16v = (_Float16*)(ws + (size_t)(20 << 20));
    _Float16* w16o = (_Float16*)(ws + (size_t)(22 << 20));
    _Float16* qh16 = (_Float16*)(ws + (size_t)(24 << 20));
    _Float16* kh16 = (_Float16*)(ws + (size_t)(32 << 20));
    _Float16* vt16 = (_Float16*)(ws + (size_t)(40 << 20));
    _Float16* ao16 = (_Float16*)(ws + (size_t)(48 << 20));

    cvt_all<<<6144, 256, 0, stream>>>(q, kv, Wq, Wk, Wv, Wo,
                                      q16, kv16, w16q, w16k, w16v, w16o);

    proj_qkv<<<768, 256, 0, stream>>>(q16, kv16, w16q, w16k, w16v,
                                      bq, bk, bv, qh16, kh16, vt16);

    attn_mfma<<<1024, 128, 0, stream>>>(qh16, kh16, vt16, ao16);

    gemm_o<<<512, 256, 0, stream>>>(ao16, w16o, bo, (float*)d_out);
}